// Round 9
// baseline (278.580 us; speedup 1.0000x reference)
//
#include <hip/hip_runtime.h>
#include <math.h>

#define S_LEN 2048
#define D_DIM 128
#define BHN   32
#define NKT   32   // prep KV tiles of 64
#define NGRP  8    // per-XCD work groups
#define ITEMS_PER_GRP 256   // 4 bh x 64 q-tiles of 32 rows
#define LOG2E 1.44269504088896340736f

typedef _Float16 f16;
typedef __attribute__((ext_vector_type(4))) _Float16 f16x4;
typedef __attribute__((ext_vector_type(8))) _Float16 f16x8;
typedef __attribute__((ext_vector_type(16))) float   f32x16;

// per-XCD-group work counters (zeroed by prep_kernel; per-WAVE consumption)
__device__ int g_counters[NGRP];

__device__ __forceinline__ void async_cp16(const void* g, void* l) {
  __builtin_amdgcn_global_load_lds(
      (const __attribute__((address_space(1))) unsigned int*)g,
      (__attribute__((address_space(3))) unsigned int*)l,
      16, 0, 0);
}

__device__ __forceinline__ uint32_t pk2(float a, float b) {
  f16 h[2] = {(f16)a, (f16)b};
  uint32_t u; __builtin_memcpy(&u, h, 4); return u;
}

// ---- fused prepass: one block per (bh, jt) 64-row tile (UNCHANGED; proven).
__global__ __launch_bounds__(256) void prep_kernel(const float* __restrict__ k,
                                                   const float* __restrict__ v,
                                                   f16* __restrict__ kw,
                                                   f16* __restrict__ vtw) {
  __shared__ f16 Vimg[D_DIM * 64];   // 16 KB, final swizzled V^T image

  if (blockIdx.x == 0 && threadIdx.x < NGRP) g_counters[threadIdx.x] = 0;

  const int bx = blockIdx.x;
  const int bh = bx >> 5;
  const int jt = bx & 31;
  const int t  = threadIdx.x;

  // ---- K: fp32 -> f16 swizzled tile [r(64)][chunk'(16)][8], chunk' = kd^(r&15)
  {
    const float* kbase = k + ((size_t)bh * S_LEN + jt * 64) * D_DIM;
    f16* ktile = kw + (((size_t)bh * NKT + jt) * 64) * (size_t)D_DIM;
#pragma unroll
    for (int i = 0; i < 4; ++i) {
      int unit = i * 256 + t;
      int kd = unit & 15;
      int r  = unit >> 4;
      const float* src = kbase + r * D_DIM + kd * 8;
      float4 a = *(const float4*)src;
      float4 b = *(const float4*)(src + 4);
      f16x8 vv;
      vv[0]=(f16)a.x; vv[1]=(f16)a.y; vv[2]=(f16)a.z; vv[3]=(f16)a.w;
      vv[4]=(f16)b.x; vv[5]=(f16)b.y; vv[6]=(f16)b.z; vv[7]=(f16)b.w;
      *(f16x8*)(ktile + r * D_DIM + ((kd ^ (r & 15)) * 8)) = vv;
    }
  }

  // ---- V: fp32 -> f16 transposed tile [d(128)][chunk'(8)][8], chunk' = kc^(d&7)
  {
    const int rq = t >> 4;
    const int dg = t & 15;
    const float* base = v + (((size_t)bh * S_LEN + jt * 64 + rq * 4) * D_DIM + dg * 8);
    float rows[4][8];
#pragma unroll
    for (int rr = 0; rr < 4; ++rr) {
      float4 aa = *(const float4*)(base + rr * D_DIM);
      float4 bb = *(const float4*)(base + rr * D_DIM + 4);
      rows[rr][0]=aa.x; rows[rr][1]=aa.y; rows[rr][2]=aa.z; rows[rr][3]=aa.w;
      rows[rr][4]=bb.x; rows[rr][5]=bb.y; rows[rr][6]=bb.z; rows[rr][7]=bb.w;
    }
    const int kc = rq >> 1;
    const int kk = (rq & 1) * 4;
#pragma unroll
    for (int dd0 = 0; dd0 < 8; ++dd0) {
      int dd = (dd0 + dg) & 7;
      int d  = dg * 8 + dd;
      f16x4 p;
      p[0]=(f16)rows[0][dd]; p[1]=(f16)rows[1][dd];
      p[2]=(f16)rows[2][dd]; p[3]=(f16)rows[3][dd];
      *(f16x4*)(Vimg + d * 64 + ((kc ^ dd) * 8) + kk) = p;
    }
    __syncthreads();
    f16* vtile = vtw + ((size_t)bh * NKT + jt) * (size_t)(D_DIM * 64);
#pragma unroll
    for (int i = 0; i < 4; ++i) {
      int idx = i * 256 + t;
      *(f16x8*)(vtile + idx * 8) = *(const f16x8*)(Vimg + idx * 8);
    }
  }
}

// ---- R9: BARRIER-FREE independent-wave flash attention.
// One wave = one 32-row Q-tile item; KVBLK=32; private 16KB LDS slice per wave
// (K 8KB + V 8KB). No __syncthreads anywhere in the loop — staging is ordered
// by counted s_waitcnt vmcnt only (the wave is its own producer AND consumer).
// Datapath = R8's verified 32x32 swapped-QK, shrunk to one S-tile:
//   QK: A=K[kv32], B=Q -> lane holds 16 of 32 kv for q-row ql (partner lane^32
//       holds the rest); softmax = 15-op tree + 1 shfl_xor(32).
//   PV: P in-register (4 shfl_xor/iter, R8-verified quad exchange).
// V half-tile staged by per-lane-src gather (guide: gload_lds src IS per-lane)
// into [d(128)][slot'(4)][8], slot' = slot^(d&3); per-lane src offset is
// CONSTANT across the 8 loads (d&3, d&7 invariant under i*16). Read pattern
// (d*4 + (slot^(d&3)))*16B puts exactly 8 lanes on each 16B slot = the b128
// norm (conflict-free). K half-tiles are contiguous in the prep layout
// (j*4096 elems), swizzle formula unchanged ((ql&15) invariant).
// Scheduling: 2048 items, per-XCD queues, per-WAVE atomic grab, LPT heavy
// first; grid 1024 (2 resident blocks/CU + HW backfill of pending blocks).
__global__ __launch_bounds__(256) void attn_kernel(const float* __restrict__ q,
                                                   const f16* __restrict__ kw,
                                                   const f16* __restrict__ vtw,
                                                   const float* __restrict__ am,
                                                   const float* __restrict__ hm,
                                                   float* __restrict__ out) {
  __shared__ f16 lds[4][8192];   // per-wave slice: [0..4095]=K, [4096..8191]=V

  const int grp  = blockIdx.x & (NGRP - 1);
  const int t    = threadIdx.x;
  const int wv   = t >> 6;
  const int lane = t & 63;
  const int ql   = lane & 31;
  const int hi   = lane >> 5;

  f16* Kb = &lds[wv][0];
  f16* Vb = &lds[wv][4096];

  // per-lane constant V-gather offsets (elems), one per kv-half kh:
  // d = i*16 + (l>>2); slot = (l&3)^((l>>2)&3); chunk64' = (kh*4+slot)^((l>>2)&7)
  const int l4   = lane >> 2;
  const int slt  = (lane & 3) ^ (l4 & 3);
  const int voff0 = l4 * 64 + (((0 * 4 + slt) ^ (l4 & 7)) * 8);
  const int voff1 = l4 * 64 + (((1 * 4 + slt) ^ (l4 & 7)) * 8);

  for (;;) {
    int vitem = 0;
    if (lane == 0) vitem = atomicAdd(&g_counters[grp], 1);
    const int r = __builtin_amdgcn_readfirstlane(vitem);
    if (r >= ITEMS_PER_GRP) break;

    const int qt = 63 - (r >> 2);         // LPT: heaviest first
    const int bh = grp * 4 + (r & 3);     // group-local bh -> L2 locality
    const int b  = bh >> 4;
    const int h  = bh & 15;
    const int qrow = qt * 32 + ql;        // this lane's q row (global within bh)

    // Q fragments (pre-scaled by log2e): qf[ks] = Q[qrow][ks*16+hi*8 .. +7]
    f16x8 qf[8];
    {
      const float* qsrc = q + (((size_t)bh * S_LEN + qrow) * D_DIM + hi * 8);
#pragma unroll
      for (int ks = 0; ks < 8; ++ks) {
        float4 a  = *(const float4*)(qsrc + ks * 16);
        float4 bb = *(const float4*)(qsrc + ks * 16 + 4);
        f16x8 vv;
        vv[0]=(f16)(a.x*LOG2E);  vv[1]=(f16)(a.y*LOG2E);  vv[2]=(f16)(a.z*LOG2E);  vv[3]=(f16)(a.w*LOG2E);
        vv[4]=(f16)(bb.x*LOG2E); vv[5]=(f16)(bb.y*LOG2E); vv[6]=(f16)(bb.z*LOG2E); vv[7]=(f16)(bb.w*LOG2E);
        qf[ks] = vv;
      }
    }

    const float hmv  = hm[h];
    const float* amp = am + (size_t)b * S_LEN;
    const f16* kbh = kw  + (size_t)bh * NKT * 8192;   // [j32 half-tiles of 4096]
    const f16* vbh = vtw + (size_t)bh * NKT * 8192;   // [jt64 tiles of 8192]

    f32x16 oacc[4];   // [dt]: O[row=(reg&3)+8*(reg>>2)+4hi][d=dt*32+ql]
#pragma unroll
    for (int dt = 0; dt < 4; ++dt)
#pragma unroll
      for (int rr = 0; rr < 16; ++rr) oacc[dt][rr] = 0.f;
    float mrow = -INFINITY;
    float lrow = 0.f;   // this lane's 16-kv partials; partner+self combined at end

    for (int j = 0; j <= qt; ++j) {
      // prior iter's ds_reads fully consumed before overwriting the slice
      asm volatile("s_waitcnt lgkmcnt(0)" ::: "memory");
      __builtin_amdgcn_sched_barrier(0);

      // attn_mask: lane's kv rows rg*8+hi*4+{0..3}
      float4 amv[4];
#pragma unroll
      for (int rg = 0; rg < 4; ++rg)
        amv[rg] = *(const float4*)(amp + j * 32 + rg * 8 + hi * 4);
      __builtin_amdgcn_sched_barrier(0);

      // stage K half-tile (contiguous): 8 x 16B per lane
      {
        const f16* kg = kbh + (size_t)j * 4096 + lane * 8;
#pragma unroll
        for (int i = 0; i < 8; ++i) async_cp16(kg + i * 512, Kb + (i * 64 + lane) * 8);
      }
      __builtin_amdgcn_sched_barrier(0);

      // stage V half-tile: per-lane gather from prep 64-kv image
      {
        const f16* vg = vbh + (size_t)(j >> 1) * 8192 + ((j & 1) ? voff1 : voff0);
#pragma unroll
        for (int i = 0; i < 8; ++i) async_cp16(vg + i * 1024, Vb + (i * 64 + lane) * 8);
      }
      __builtin_amdgcn_sched_barrier(0);

      // amv(4)+K(8) retired (oldest 12); V(8) stays in flight under QK+softmax
      asm volatile("s_waitcnt vmcnt(8)" ::: "memory");
      __builtin_amdgcn_sched_barrier(0);

      // S^T = K (Q*log2e)^T : one 32x32 tile (kv 0..31 of this j)
      f32x16 s;
#pragma unroll
      for (int rr = 0; rr < 16; ++rr) s[rr] = 0.f;
#pragma unroll
      for (int ks = 0; ks < 8; ++ks) {
        const f16x8 kf = *(const f16x8*)(Kb + ql * 128 + (((ks * 2 + hi) ^ (ql & 15)) * 8));
        s = __builtin_amdgcn_mfma_f32_32x32x16_f16(kf, qf[ks], s, 0, 0, 0);
      }

      if (j == qt) {   // causal mask, diagonal tile: kv_in > q_in
#pragma unroll
        for (int reg = 0; reg < 16; ++reg) {
          const int kv = (reg & 3) + 8 * (reg >> 2) + 4 * hi;
          if (kv > ql) s[reg] = -INFINITY;
        }
      }
      // additive mask (exp2 base)
#pragma unroll
      for (int rg = 0; rg < 4; ++rg) {
        s[rg*4+0] = fmaf(amv[rg].x, LOG2E, s[rg*4+0]);
        s[rg*4+1] = fmaf(amv[rg].y, LOG2E, s[rg*4+1]);
        s[rg*4+2] = fmaf(amv[rg].z, LOG2E, s[rg*4+2]);
        s[rg*4+3] = fmaf(amv[rg].w, LOG2E, s[rg*4+3]);
      }

      // row max: balanced tree over 16 + partner
      float m4[4];
#pragma unroll
      for (int g = 0; g < 4; ++g)
        m4[g] = fmaxf(fmaxf(s[g*4+0], s[g*4+1]), fmaxf(s[g*4+2], s[g*4+3]));
      float m16 = fmaxf(fmaxf(m4[0], m4[1]), fmaxf(m4[2], m4[3]));
      m16 = fmaxf(m16, __shfl_xor(m16, 32));

      // T13 defer-max
      if (!__all(m16 <= mrow + 8.0f)) {
        float mnew  = fmaxf(mrow, m16);
        float alpha = exp2f(mrow - mnew);
        mrow = mnew;
        lrow *= alpha;
        float av[16];
#pragma unroll
        for (int reg = 0; reg < 16; ++reg)
          av[reg] = __shfl(alpha, (reg & 3) + 8 * (reg >> 2) + 4 * hi);
#pragma unroll
        for (int dt = 0; dt < 4; ++dt)
#pragma unroll
          for (int reg = 0; reg < 16; ++reg) oacc[dt][reg] *= av[reg];
      }

      // exp2 + partial sum
      float ps = 0.f;
#pragma unroll
      for (int g = 0; g < 4; ++g) {
        s[g*4+0]=exp2f(s[g*4+0]-mrow); s[g*4+1]=exp2f(s[g*4+1]-mrow);
        s[g*4+2]=exp2f(s[g*4+2]-mrow); s[g*4+3]=exp2f(s[g*4+3]-mrow);
        ps += (s[g*4+0]+s[g*4+1]) + (s[g*4+2]+s[g*4+3]);
      }
      lrow += ps;

      // pack P pairs: cc[rg] covers kv rg*8+4hi+{0..3}
      uint32_t cc[4][2];
#pragma unroll
      for (int rg = 0; rg < 4; ++rg) {
        cc[rg][0] = pk2(s[rg*4+0], s[rg*4+1]);
        cc[rg][1] = pk2(s[rg*4+2], s[rg*4+3]);
      }

      // A-frags: af[ks2] = P[ql][ks2*16+hi*8+{0..7}]
      //  own quad (==4hi mod 8): rg = 2*ks2+hi; send quad: rg = 2*ks2+1-hi
      f16x8 af[2];
#pragma unroll
      for (int ks2 = 0; ks2 < 2; ++ks2) {
        const int o_rg = 2 * ks2 + hi;
        const int s_rg = 2 * ks2 + 1 - hi;
        uint32_t xA = (uint32_t)__shfl_xor((int)cc[s_rg][0], 32);
        uint32_t xB = (uint32_t)__shfl_xor((int)cc[s_rg][1], 32);
        uint32_t u[4];
        u[0] = hi ? xA : cc[o_rg][0];
        u[1] = hi ? xB : cc[o_rg][1];
        u[2] = hi ? cc[o_rg][0] : xA;
        u[3] = hi ? cc[o_rg][1] : xB;
        __builtin_memcpy(&af[ks2], u, 16);
      }

      // V resident (issued one phase ago; QK+softmax covered its latency)
      asm volatile("s_waitcnt vmcnt(0)" ::: "memory");
      __builtin_amdgcn_sched_barrier(0);

      // O += P V : bf = V^T[d=dt*32+ql][kv=(ks2*2+hi)*8+{0..7}]
#pragma unroll
      for (int dt = 0; dt < 4; ++dt) {
        const int d4 = (dt * 32 + ql) * 4;
#pragma unroll
        for (int ks2 = 0; ks2 < 2; ++ks2) {
          const f16x8 bf = *(const f16x8*)(Vb + (d4 + ((ks2 * 2 + hi) ^ (ql & 3))) * 8);
          oacc[dt] = __builtin_amdgcn_mfma_f32_32x32x16_f16(af[ks2], bf, oacc[dt], 0, 0, 0);
        }
      }
    }

    // epilogue: l = own + partner; out = hm * O / l
    lrow += __shfl_xor(lrow, 32);
    const float linv = hmv / lrow;
    float* ob = out + (((size_t)bh * S_LEN + qt * 32) * D_DIM);
#pragma unroll
    for (int reg = 0; reg < 16; ++reg) {
      const int row = (reg & 3) + 8 * (reg >> 2) + 4 * hi;
      const float rv = __shfl(linv, row);
#pragma unroll
      for (int dt = 0; dt < 4; ++dt)
        ob[row * D_DIM + dt * 32 + ql] = oacc[dt][reg] * rv;
    }
  }
}

extern "C" void kernel_launch(void* const* d_in, const int* in_sizes, int n_in,
                              void* d_out, int out_size, void* d_ws, size_t ws_size,
                              hipStream_t stream) {
  const float* q  = (const float*)d_in[0];
  const float* k  = (const float*)d_in[1];
  const float* v  = (const float*)d_in[2];
  const float* am = (const float*)d_in[3];
  const float* hm = (const float*)d_in[4];
  float* out = (float*)d_out;

  f16* kw  = (f16*)d_ws;                              // 16.78 MB
  f16* vtw = kw + (size_t)BHN * S_LEN * D_DIM;        // 16.78 MB

  prep_kernel<<<1024, 256, 0, stream>>>(k, v, kw, vtw);
  attn_kernel<<<1024, 256, 0, stream>>>(q, kw, vtw, am, hm, out);
}